// Round 9
// baseline (591.761 us; speedup 1.0000x reference)
//
#include <hip/hip_runtime.h>
#include <cmath>

#define B_ 16
#define N_ 48
#define HID_ 64
#define NL_ 128
#define NNODE_ (B_*N_)        // 768
#define NEDGE_ (B_*N_*N_)     // 36864

__device__ __forceinline__ float sigmoidf_(float x){ return 1.0f/(1.0f+expf(-x)); }

// ---------------------------------------------------------------------------
// K_PM (R6-measured form): blocks [0,576): edge-MLP relu2 (4-edge x 8-out
// register tile). Blocks [576,961): prep (A/B sums, bias sums, h_first, mask,
// GRU weight transposes).
// ---------------------------------------------------------------------------
__global__ __launch_bounds__(256) void k_pm(
    const float* __restrict__ ein, const float* __restrict__ w0, const float* __restrict__ b0,
    const float* __restrict__ w1, const float* __restrict__ b1,
    const float* __restrict__ w2, const float* __restrict__ b2,
    const float* __restrict__ h0,
    const float* __restrict__ wih, const float* __restrict__ whh,
    float* __restrict__ relu2,
    float* __restrict__ A, float* __restrict__ Bm,
    float* __restrict__ Ab, float* __restrict__ Bb,
    float* __restrict__ hfirst, float* __restrict__ mask,
    float* __restrict__ wihT, float* __restrict__ whhT)
{
    __shared__ __align__(16) float x1s[64*132];
    int tid = threadIdx.x;

    if (blockIdx.x < 576){
        // ================= edge MLP =================
        int et = tid & 15, ot = tid >> 4;
        int o0 = ot * 8;
        size_t e0 = (size_t)blockIdx.x * 64;

        // ---- layer 1 ----
        float acc[4][8];
        {
            float4 ba = *(const float4*)&b0[o0];
            float4 bb = *(const float4*)&b0[o0 + 4];
            #pragma unroll
            for (int q = 0; q < 4; q++){
                acc[q][0]=ba.x; acc[q][1]=ba.y; acc[q][2]=ba.z; acc[q][3]=ba.w;
                acc[q][4]=bb.x; acc[q][5]=bb.y; acc[q][6]=bb.z; acc[q][7]=bb.w;
            }
        }
        #pragma unroll
        for (int i4 = 0; i4 < 4; i4++){
            float4 ev[4];
            #pragma unroll
            for (int q = 0; q < 4; q++)
                ev[q] = *(const float4*)&ein[(e0 + q*16 + et)*16 + i4*4];
            float wr[4][8];
            #pragma unroll
            for (int d = 0; d < 4; d++){
                *(float4*)&wr[d][0] = *(const float4*)&w0[(i4*4+d)*128 + o0];
                *(float4*)&wr[d][4] = *(const float4*)&w0[(i4*4+d)*128 + o0 + 4];
            }
            #pragma unroll
            for (int q = 0; q < 4; q++){
                #pragma unroll
                for (int r2 = 0; r2 < 8; r2++)
                    acc[q][r2] += ev[q].x*wr[0][r2] + ev[q].y*wr[1][r2]
                                + ev[q].z*wr[2][r2] + ev[q].w*wr[3][r2];
            }
        }
        #pragma unroll
        for (int q = 0; q < 4; q++){
            int e = q*16 + et;
            float4 s0 = make_float4(fmaxf(acc[q][0],0.f), fmaxf(acc[q][1],0.f),
                                    fmaxf(acc[q][2],0.f), fmaxf(acc[q][3],0.f));
            float4 s1 = make_float4(fmaxf(acc[q][4],0.f), fmaxf(acc[q][5],0.f),
                                    fmaxf(acc[q][6],0.f), fmaxf(acc[q][7],0.f));
            *(float4*)&x1s[e*132 + o0]     = s0;
            *(float4*)&x1s[e*132 + o0 + 4] = s1;
        }
        __syncthreads();

        // ---- layer 2 ----
        float a2[4][8];
        {
            float4 ba = *(const float4*)&b1[o0];
            float4 bb = *(const float4*)&b1[o0 + 4];
            #pragma unroll
            for (int q = 0; q < 4; q++){
                a2[q][0]=ba.x; a2[q][1]=ba.y; a2[q][2]=ba.z; a2[q][3]=ba.w;
                a2[q][4]=bb.x; a2[q][5]=bb.y; a2[q][6]=bb.z; a2[q][7]=bb.w;
            }
        }
        for (int i4 = 0; i4 < 32; i4++){
            int i = i4*4;
            float wr[4][8];
            #pragma unroll
            for (int d = 0; d < 4; d++){
                *(float4*)&wr[d][0] = *(const float4*)&w1[(size_t)(i+d)*128 + o0];
                *(float4*)&wr[d][4] = *(const float4*)&w1[(size_t)(i+d)*128 + o0 + 4];
            }
            #pragma unroll
            for (int q = 0; q < 4; q++){
                float4 xv = *(const float4*)&x1s[(q*16 + et)*132 + i];
                #pragma unroll
                for (int r2 = 0; r2 < 8; r2++)
                    a2[q][r2] += xv.x*wr[0][r2] + xv.y*wr[1][r2]
                               + xv.z*wr[2][r2] + xv.w*wr[3][r2];
            }
        }
        #pragma unroll
        for (int q = 0; q < 4; q++){
            size_t e = e0 + q*16 + et;
            float4 s0 = make_float4(fmaxf(a2[q][0],0.f), fmaxf(a2[q][1],0.f),
                                    fmaxf(a2[q][2],0.f), fmaxf(a2[q][3],0.f));
            float4 s1 = make_float4(fmaxf(a2[q][4],0.f), fmaxf(a2[q][5],0.f),
                                    fmaxf(a2[q][6],0.f), fmaxf(a2[q][7],0.f));
            *(float4*)&relu2[e*128 + o0]     = s0;
            *(float4*)&relu2[e*128 + o0 + 4] = s1;
        }
    } else {
        // ================= prep =================
        int idx = (blockIdx.x - 576)*256 + tid;
        if (idx < 24576) {
            int r = idx >> 13, c = (idx >> 6) & 127, m = idx & 63;
            int t = 48 - 16*r;
            const float* src = w2 + c*4096 + m*64;
            float a = 0.f, b = 0.f;
            #pragma unroll
            for (int k4 = 0; k4 < 16; k4++){
                float4 v = *(const float4*)&src[k4*4];
                float s = v.x + v.y + v.z + v.w;
                if (k4*4 < t) a += s; else b += s;
            }
            A[idx] = a; Bm[idx] = b;
        } else if (idx < 24768) {
            int i2 = idx - 24576;
            int r = i2 >> 6, m = i2 & 63;
            int t = 48 - 16*r;
            const float* src = b2 + m*64;
            float a = 0.f, b = 0.f;
            #pragma unroll
            for (int k4 = 0; k4 < 16; k4++){
                float4 v = *(const float4*)&src[k4*4];
                float s = v.x + v.y + v.z + v.w;
                if (k4*4 < t) a += s; else b += s;
            }
            Ab[i2] = a; Bb[i2] = b;
        } else if (idx < 73920) {
            int i3 = idx - 24768;
            int node = i3 >> 6, m = i3 & 63;
            hfirst[i3] = (m < 32) ? h0[node*32 + m] : 0.f;
            if (m == 0) {
                float s = 0.f;
                #pragma unroll
                for (int k = 0; k < 32; k++) s += h0[node*32 + k];
                mask[node] = (s > 0.f) ? 1.f : 0.f;
            }
        } else if (idx < 98496) {
            int i4 = idx - 73920;
            if (i4 < 12288) {
                int k = i4 / 192, col = i4 - k*192;
                wihT[i4] = wih[col*64 + k];
            } else {
                int i5 = i4 - 12288;
                int k = i5 / 192, col = i5 - k*192;
                whhT[i5] = whh[col*64 + k];
            }
        }
    }
}

// ---------------------------------------------------------------------------
// K3: ALL 3 layers, one block per BATCH (16 blocks x 1024 threads). All
// cross-node dependencies are in-block -> plain __syncthreads(), no grid sync.
// Per layer: A) wA/wB=g*h + sums; B) U/V from relu2 (12 waves) || gh GEMM
// (4 waves, whhT from L2); C) agg = U@A+V@B (register-tiled, ds_add partials);
// D) gi from LDS-staged wihT + fused GRU nonlinearity, hs updated in place.
// LDS ~130 KB; scr[12288] is U/V in phases B/C and staged wihT in phase D.
// ---------------------------------------------------------------------------
__global__ __launch_bounds__(1024) void k_layers(
    const float* __restrict__ hfirst, float* __restrict__ hT,
    const float* __restrict__ relu2,
    const float* __restrict__ A, const float* __restrict__ Bm,
    const float* __restrict__ Ab, const float* __restrict__ Bb,
    const float* __restrict__ g, const float* __restrict__ mask,
    const float* __restrict__ wihT, const float* __restrict__ whhT,
    const float* __restrict__ bih, const float* __restrict__ bhh)
{
    __shared__ float hs[3072];                    // 12 KB  h for 48 nodes
    __shared__ float wAs[48*49], wBs[48*49];      // 18.4 KB (stride 49: CF)
    __shared__ __align__(16) float scr[12288];    // 48 KB  U/V, then wihT
    __shared__ float aggS[3072];                  // 12 KB
    __shared__ float ghS[9216];                   // 36 KB  h-side gates
    __shared__ float sA[48], sB[48], mkS[48];

    const int b = blockIdx.x, base = b*48;
    const int tid = threadIdx.x;
    float* U = scr;
    float* V = scr + 6144;

    for (int t = tid; t < 3072; t += 1024) hs[t] = hfirst[(size_t)base*64 + t];
    if (tid < 48) mkS[tid] = mask[base + tid];
    __syncthreads();

    for (int L = 0; L < 3; L++){
        // ---------- A: wA/wB = g*h, zero agg ----------
        #pragma unroll
        for (int rd = 0; rd < 3; rd++){
            int t = rd*1024 + tid;
            if (t < 2304){
                int i = t / 48, j = t - i*48;
                int p0 = j + j/3;
                float gv = g[(size_t)(base+i)*48 + j];
                wAs[i*49+j] = gv * hs[i*64 + p0];
                wBs[i*49+j] = gv * hs[i*64 + p0 + 1];
            }
            aggS[t] = 0.f;
        }
        __syncthreads();
        if (tid < 48){
            float s = 0.f;
            #pragma unroll
            for (int i = 0; i < 48; i++) s += wAs[i*49+tid];
            sA[tid] = s;
        } else if (tid >= 64 && tid < 112){
            int j = tid - 64;
            float s = 0.f;
            #pragma unroll
            for (int i = 0; i < 48; i++) s += wBs[i*49+j];
            sB[j] = s;
        }
        __syncthreads();

        // ---------- B: U/V (waves 0-11)  ||  gh GEMM (waves 12-15) ----------
        if (tid < 768){
            #pragma unroll
            for (int p = 0; p < 2; p++){
                int pt = p*768 + tid;                 // (j, c4) point, 0..1535
                int j = pt >> 5, c4 = (pt & 31) << 2;
                const float* src = relu2 + ((size_t)base*48 + j)*128 + c4;
                float4 aU = make_float4(0.f,0.f,0.f,0.f);
                float4 aV = make_float4(0.f,0.f,0.f,0.f);
                #pragma unroll 8
                for (int i = 0; i < 48; i++){
                    float4 v = *(const float4*)&src[(size_t)i*6144];
                    float wa = wAs[i*49+j], wb = wBs[i*49+j];
                    aU.x += wa*v.x; aU.y += wa*v.y; aU.z += wa*v.z; aU.w += wa*v.w;
                    aV.x += wb*v.x; aV.y += wb*v.y; aV.z += wb*v.z; aV.w += wb*v.w;
                }
                *(float4*)&U[j*128 + c4] = aU;
                *(float4*)&V[j*128 + c4] = aV;
            }
        } else {
            int t2 = tid - 768;
            int og = t2 & 63, q = t2 >> 6;            // q 0..3: 12 j's each
            float ar[12], az[12], an[12];
            {
                float b0v = bhh[og], b1v = bhh[64+og], b2v = bhh[128+og];
                #pragma unroll
                for (int t16 = 0; t16 < 12; t16++){ ar[t16]=b0v; az[t16]=b1v; an[t16]=b2v; }
            }
            #pragma unroll 2
            for (int k = 0; k < 64; k++){
                float w0v = whhT[k*192 + og];
                float w1v = whhT[k*192 + 64 + og];
                float w2v = whhT[k*192 + 128 + og];
                #pragma unroll
                for (int t16 = 0; t16 < 12; t16++){
                    float h = hs[(q*12 + t16)*64 + k];
                    ar[t16] += h*w0v; az[t16] += h*w1v; an[t16] += h*w2v;
                }
            }
            #pragma unroll
            for (int t16 = 0; t16 < 12; t16++){
                int j = q*12 + t16;
                ghS[j*192 + og]       = ar[t16];
                ghS[j*192 + 64 + og]  = az[t16];
                ghS[j*192 + 128 + og] = an[t16];
            }
        }
        __syncthreads();

        // ---------- C: agg = U@A_r + V@B_r  (thread = (m, c-group)) ----------
        {
            int m = tid & 63, cq = tid >> 6;          // cq 0..15
            #pragma unroll
            for (int rr = 0; rr < 3; rr++){
                float acc[16];
                #pragma unroll
                for (int t16 = 0; t16 < 16; t16++) acc[t16] = 0.f;
                #pragma unroll
                for (int cc = 0; cc < 8; cc++){
                    int c = cq*8 + cc;
                    float av = A [rr*8192 + c*64 + m];
                    float bv = Bm[rr*8192 + c*64 + m];
                    #pragma unroll
                    for (int t16 = 0; t16 < 16; t16++){
                        int j = rr + 3*t16;
                        acc[t16] += U[j*128 + c]*av + V[j*128 + c]*bv;
                    }
                }
                #pragma unroll
                for (int t16 = 0; t16 < 16; t16++)
                    atomicAdd(&aggS[(rr + 3*t16)*64 + m], acc[t16]);
            }
        }
        __syncthreads();
        #pragma unroll
        for (int rd = 0; rd < 3; rd++){
            int t = rd*1024 + tid;
            int j = t >> 6, m = t & 63, r = j % 3;
            aggS[t] += sA[j]*Ab[r*64 + m] + sB[j]*Bb[r*64 + m];
        }
        __syncthreads();

        // ---------- D: stage wihT over U/V, gi GEMM + fused GRU ----------
        #pragma unroll
        for (int q4 = 0; q4 < 3; q4++){
            int f = q4*1024 + tid;                    // 0..3071 float4s
            *(float4*)&scr[f*4] = *(const float4*)&wihT[(size_t)f*4];
        }
        __syncthreads();
        {
            int og = tid & 63, jp = tid >> 6;         // jp 0..15 -> j = jp*3+d
            float gr[3], gz[3], gn[3];
            {
                float bi0 = bih[og], bi1 = bih[64+og], bi2 = bih[128+og];
                #pragma unroll
                for (int d = 0; d < 3; d++){ gr[d]=bi0; gz[d]=bi1; gn[d]=bi2; }
            }
            #pragma unroll 2
            for (int k = 0; k < 64; k++){
                float w0v = scr[k*192 + og];
                float w1v = scr[k*192 + 64 + og];
                float w2v = scr[k*192 + 128 + og];
                #pragma unroll
                for (int d = 0; d < 3; d++){
                    float a = aggS[(jp*3 + d)*64 + k];
                    gr[d] += a*w0v; gz[d] += a*w1v; gn[d] += a*w2v;
                }
            }
            float hnew[3];
            #pragma unroll
            for (int d = 0; d < 3; d++){
                int j = jp*3 + d;
                float rr_ = sigmoidf_(gr[d] + ghS[j*192 + og]);
                float zz  = sigmoidf_(gz[d] + ghS[j*192 + 64 + og]);
                float nn  = tanhf(gn[d] + rr_*ghS[j*192 + 128 + og]);
                hnew[d] = mkS[j]*((1.f - zz)*nn + zz*hs[j*64 + og]);
            }
            __syncthreads();
            #pragma unroll
            for (int d = 0; d < 3; d++){
                int j = jp*3 + d;
                hs[j*64 + og] = hnew[d];
                if (L == 2) hT[(size_t)(base + j)*64 + og] = hnew[d];
            }
        }
        __syncthreads();
    }
}

// ---------------------------------------------------------------------------
// K4 (R6-measured form): readout, weights staged in LDS per layer (stride 129),
// 192 blocks x 256 threads.
// ---------------------------------------------------------------------------
__device__ __forceinline__ void stage_w(const float* __restrict__ W,
                                        float* __restrict__ Ws, int rows, int tid)
{
    for (int f = tid; f < rows*32; f += 256){
        int i = f >> 5, c4 = (f & 31) << 2;
        *(float4*)&Ws[i*129 + c4] = *(const float4*)&W[(size_t)i*128 + c4];
    }
}

__device__ __forceinline__ void lds_layer(const float* __restrict__ Ws,
    const float* __restrict__ xsrc,    // LDS, row stride 132
    const float* __restrict__ bias, float* __restrict__ dst,
    int dim, int o, int ng, bool do_relu)
{
    float a0 = bias[o];
    float a1 = a0;
    #pragma unroll 8
    for (int k = 0; k < dim; k += 4){
        float4 x0 = *(const float4*)&xsrc[ng*132 + k];
        float4 x1 = *(const float4*)&xsrc[(ng+2)*132 + k];
        float w0 = Ws[(k+0)*129 + o];
        float w1 = Ws[(k+1)*129 + o];
        float w2 = Ws[(k+2)*129 + o];
        float w3 = Ws[(k+3)*129 + o];
        a0 += x0.x*w0 + x0.y*w1 + x0.z*w2 + x0.w*w3;
        a1 += x1.x*w0 + x1.y*w1 + x1.z*w2 + x1.w*w3;
    }
    if (do_relu){ a0 = fmaxf(a0, 0.f); a1 = fmaxf(a1, 0.f); }
    dst[ng*132 + o] = a0;
    dst[(ng+2)*132 + o] = a1;
}

__global__ __launch_bounds__(256, 2) void k_read(
    const float* __restrict__ hfirst, const float* __restrict__ hT,
    const float* __restrict__ mask,
    const float* __restrict__ w00, const float* __restrict__ b00,
    const float* __restrict__ w01, const float* __restrict__ b01,
    const float* __restrict__ w02, const float* __restrict__ b02,
    const float* __restrict__ w10, const float* __restrict__ b10,
    const float* __restrict__ w11, const float* __restrict__ b11,
    const float* __restrict__ w12, const float* __restrict__ b12,
    float* __restrict__ partial)
{
    __shared__ __align__(16) float Ws[128*129];   // 66 KB
    __shared__ __align__(16) float xs[4*132], ys[4*132], zs[4*132], os0[4*132];
    __shared__ float mS[4];
    int tid = threadIdx.x;
    int b = blockIdx.x / 12, gg = blockIdx.x - b*12;
    int node0 = b*48 + gg*4;
    int o = tid & 127, ng = tid >> 7;

    if (tid < 4) mS[tid] = mask[node0 + tid];
    for (int i = tid; i < 4*128; i += 256){
        int r = i >> 7, c = i & 127;
        xs[r*132 + c] = (c < 64) ? hfirst[(size_t)(node0+r)*64 + c]
                                 : hT[(size_t)(node0+r)*64 + (c - 64)];
    }
    stage_w(w00, Ws, 128, tid);                       __syncthreads();
    lds_layer(Ws, xs,      b00, ys,  128, o, ng, true);  __syncthreads();
    stage_w(w01, Ws, 128, tid);                       __syncthreads();
    lds_layer(Ws, ys,      b01, zs,  128, o, ng, true);  __syncthreads();
    stage_w(w02, Ws, 128, tid);                       __syncthreads();
    lds_layer(Ws, zs,      b02, os0, 128, o, ng, false); __syncthreads();
    stage_w(w10, Ws, 64, tid);                        __syncthreads();
    lds_layer(Ws, xs + 64, b10, ys,  64,  o, ng, true);  __syncthreads();
    stage_w(w11, Ws, 128, tid);                       __syncthreads();
    lds_layer(Ws, ys,      b11, zs,  128, o, ng, true);  __syncthreads();
    stage_w(w12, Ws, 128, tid);                       __syncthreads();
    {
        float a0 = b12[o];
        float a1 = a0;
        #pragma unroll 8
        for (int k = 0; k < 128; k += 4){
            float4 x0 = *(const float4*)&zs[ng*132 + k];
            float4 x1 = *(const float4*)&zs[(ng+2)*132 + k];
            float w0 = Ws[(k+0)*129 + o];
            float w1 = Ws[(k+1)*129 + o];
            float w2 = Ws[(k+2)*129 + o];
            float w3 = Ws[(k+3)*129 + o];
            a0 += x0.x*w0 + x0.y*w1 + x0.z*w2 + x0.w*w3;
            a1 += x1.x*w0 + x1.y*w1 + x1.z*w2 + x1.w*w3;
        }
        float s = mS[ng]   * os0[ng*132 + o]     * a0
                + mS[ng+2] * os0[(ng+2)*132 + o] * a1;
        __syncthreads();
        ys[ng*132 + o] = s;
    }
    __syncthreads();
    if (tid < 128)
        partial[(size_t)blockIdx.x*128 + tid] = ys[tid] + ys[132 + tid];
}

// ---------------------------------------------------------------------------
// K5: reduce 12 partials per batch + sigmoid
// ---------------------------------------------------------------------------
__global__ void k_final(const float* __restrict__ partial, float* __restrict__ out)
{
    int idx = blockIdx.x*256 + threadIdx.x;
    if (idx < B_*128){
        int b = idx >> 7, t = idx & 127;
        float s = 0.f;
        #pragma unroll
        for (int c = 0; c < 12; c++) s += partial[(size_t)(b*12 + c)*128 + t];
        out[idx] = 1.0f / (1.0f + expf(-s));
    }
}

// ---------------------------------------------------------------------------
extern "C" void kernel_launch(void* const* d_in, const int* in_sizes, int n_in,
                              void* d_out, int out_size, void* d_ws, size_t ws_size,
                              hipStream_t stream)
{
    (void)in_sizes; (void)n_in; (void)out_size; (void)ws_size;
    const float* g    = (const float*)d_in[0];
    const float* h0   = (const float*)d_in[1];
    const float* e    = (const float*)d_in[2];
    const float* mw0  = (const float*)d_in[3];
    const float* mb0  = (const float*)d_in[4];
    const float* mw1  = (const float*)d_in[5];
    const float* mb1  = (const float*)d_in[6];
    const float* mw2  = (const float*)d_in[7];
    const float* mb2  = (const float*)d_in[8];
    const float* wih  = (const float*)d_in[9];
    const float* whh  = (const float*)d_in[10];
    const float* bih  = (const float*)d_in[11];
    const float* bhh  = (const float*)d_in[12];
    const float* r0w0 = (const float*)d_in[13];
    const float* r0b0 = (const float*)d_in[14];
    const float* r0w1 = (const float*)d_in[15];
    const float* r0b1 = (const float*)d_in[16];
    const float* r0w2 = (const float*)d_in[17];
    const float* r0b2 = (const float*)d_in[18];
    const float* r1w0 = (const float*)d_in[19];
    const float* r1b0 = (const float*)d_in[20];
    const float* r1w1 = (const float*)d_in[21];
    const float* r1b1 = (const float*)d_in[22];
    const float* r1w2 = (const float*)d_in[23];
    const float* r1b2 = (const float*)d_in[24];
    float* out = (float*)d_out;

    float* ws     = (float*)d_ws;
    float* A      = ws;                  // 3*128*64   = 24576
    float* Bm     = A      + 24576;      //              24576
    float* Ab     = Bm     + 24576;      // 3*64       = 192
    float* Bb     = Ab     + 192;        //              192
    float* hfirst = Bb     + 192;        // 768*64     = 49152
    float* hA     = hfirst + 49152;      //              49152
    float* mask   = hA     + 49152;      //              768
    float* wihT   = mask   + 768;        // 64*192     = 12288
    float* whhT   = wihT   + 12288;      //              12288
    float* part   = whhT   + 12288;      // 192*128    = 24576
    float* relu2  = part   + 24576;      // 36864*128  = 4718592
    // total ~ 4.9M floats = 18.8 MiB

    k_pm<<<961, 256, 0, stream>>>(e, mw0, mb0, mw1, mb1, mw2, mb2, h0, wih, whh,
                                  relu2, A, Bm, Ab, Bb, hfirst, mask, wihT, whhT);
    k_layers<<<16, 1024, 0, stream>>>(hfirst, hA, relu2, A, Bm, Ab, Bb,
                                      g, mask, wihT, whhT, bih, bhh);
    k_read<<<192, 256, 0, stream>>>(hfirst, hA, mask,
                                    r0w0, r0b0, r0w1, r0b1, r0w2, r0b2,
                                    r1w0, r1b0, r1w1, r1b1, r1w2, r1b2, part);
    k_final<<<8, 256, 0, stream>>>(part, out);
}